// Round 2
// baseline (111.826 us; speedup 1.0000x reference)
//
#include <hip/hip_runtime.h>
#include <math.h>

// ---------------------------------------------------------------------------
// TropicalMLP: h_i = logsumexp_j(x_j + w_ij) + b_i = log(sum_j e^x_j e^w_ij)+b_i
// Row-independent network: one block owns 2 batch rows, runs all 3 layers +
// 2 tropical-LNs with only __syncthreads(). Two dispatches.
// fp8 e4m3 operands via mfma_f32_16x16x32_fp8_fp8.
// Scaling keeps fp8 normal-range: layer1 A = 4*exp(x) (+ln4 cancels in LN1
// median); layers2/3 A = 64*exp(y-cm) (+ln64 cancels in LN2; subtracted in
// final epilogue). B = exp(w) in [0.6,1.6] needs no scale.
// Weights pre-exp'd + permuted to MFMA-fragment order (512B-coalesced loads).
// R8: B-prefetch for each layer hoisted ABOVE the preceding barrier.
// R9: bitonic sort as compact runtime loops (I-footprint fix; -10%).
// R10: TLP DOUBLING. Counters showed pure latency-bound (MfmaUtil 4%,
// VALUBusy 17%, HBM 1.3%, occ 20% = 1 block/CU): the serial
// exp->GEMM->LN->GEMM->LN->GEMM chain has only 2 waves/SIMD to hide
// ds_bpermute (~150cyc/round x 21 rounds) and L2/L3 B-load latency.
// Now 2 rows/block x 512 blocks = 2 blocks/CU = 16 waves/CU: two
// independent chains interleave per SIMD. MFMA work doubles (2 rows dup 8x
// in the 16-row A slot) -- irrelevant at 4% MfmaUtil.
// ---------------------------------------------------------------------------

typedef float v4f __attribute__((ext_vector_type(4)));

#define ELS_B 528                  // bytes per LDS A-row (16B pad: 2-way banks = free)
#define LN64f 4.1588830833596715f  // ln(64)

__device__ __forceinline__ int pk4_fp8(float a, float b, float c, float d) {
    int p = __builtin_amdgcn_cvt_pk_fp8_f32(a, b, 0, 0);      // bytes 0,1
    p = __builtin_amdgcn_cvt_pk_fp8_f32(c, d, p, 1);          // bytes 2,3
    return p;
}

// D1: exp + fp8 + fragment reorder. Global 16-col tile S, k-step t (32 k),
// lane l = q*16+r:  Ef[(S*16+t)*512 + l*8 + j] = fp8(exp(W[S*16+r][t*32+q*8+j]))
// S: 0..31 -> w1, 32..63 -> w2, 64..79 -> w3 (contiguous per layer, in bytes).
__global__ __launch_bounds__(256) void expW_frag(const float* __restrict__ w1,
                                                 const float* __restrict__ w2,
                                                 const float* __restrict__ w3,
                                                 uint8_t* __restrict__ Ef) {
    int u = blockIdx.x * 256 + threadIdx.x;          // 0..81919 (320 blocks)
    int lane = u & 63, t = (u >> 6) & 15, S = u >> 10;
    int r = lane & 15, q = lane >> 4;
    const float* w; int tile;
    if (S < 32)      { w = w1; tile = S; }
    else if (S < 64) { w = w2; tile = S - 32; }
    else             { w = w3; tile = S - 64; }
    const float* src = w + (tile * 16 + r) * 512 + t * 32 + q * 8;
    float4 a = *reinterpret_cast<const float4*>(src);
    float4 b = *reinterpret_cast<const float4*>(src + 4);
    int2 o;
    o.x = pk4_fp8(__expf(a.x), __expf(a.y), __expf(a.z), __expf(a.w));
    o.y = pk4_fp8(__expf(b.x), __expf(b.y), __expf(b.z), __expf(b.w));
    *reinterpret_cast<int2*>(Ef + u * 8) = o;
}

// Preload whole A operand (2 rows dup'd 8x in the 16-row slot) for all 16
// k-steps: 16 x ds_read_b64.
__device__ __forceinline__ void load_areg(const uint8_t* Els, int lane, long* areg) {
    const uint8_t* ap = Els + (lane & 1) * ELS_B + ((lane >> 4) & 3) * 8;
#pragma unroll
    for (int t = 0; t < 16; ++t)
        areg[t] = *reinterpret_cast<const long*>(ap + t * 32);
}

// Issue the first 8 k-steps of a layer's B stream (kept in flight across the
// following barrier / LN — this is the latency-hiding hoist).
template <int NSUB>
__device__ __forceinline__ void prefetchB(const uint8_t* __restrict__ bp,
                                          int s0, long bb[8][4]) {
#pragma unroll
    for (int p = 0; p < 8; ++p)
#pragma unroll
        for (int s = 0; s < NSUB; ++s)
            bb[p][s] = *reinterpret_cast<const long*>(bp + ((s0 + s) * 16 + p) * 512);
}

// C[16(dup rows) x NSUB*16 cols] over K=512, fp8 MFMA, consuming the
// prefetched pipe and rolling it forward (depth 8).
template <int NSUB>
__device__ __forceinline__ void gemm_body(const uint8_t* __restrict__ bp,
                                          int s0, const long* areg,
                                          long bb[8][4], v4f* acc) {
#pragma unroll
    for (int s = 0; s < NSUB; ++s) acc[s] = (v4f){0.f, 0.f, 0.f, 0.f};
#pragma unroll
    for (int t = 0; t < 16; ++t) {
        long a = areg[t];
        long bcur[NSUB];
#pragma unroll
        for (int s = 0; s < NSUB; ++s) bcur[s] = bb[t & 7][s];
        if (t < 8) {
#pragma unroll
            for (int s = 0; s < NSUB; ++s)
                bb[t & 7][s] =
                    *reinterpret_cast<const long*>(bp + ((s0 + s) * 16 + t + 8) * 512);
        }
#pragma unroll
        for (int s = 0; s < NSUB; ++s)
            acc[s] = __builtin_amdgcn_mfma_f32_16x16x32_fp8_fp8(a, bcur[s],
                                                                acc[s], 0, 0, 0);
    }
}

// Tropical-LN on one row (1 wave, lane-major): exact order stats via
// in-register bitonic (compact loop form); relu; subtract rowmax;
// 64*exp -> fp8 into Els.
__device__ __forceinline__ void ln_row(const float* hbuf,
                                       const float* __restrict__ lw,
                                       const float* __restrict__ lb,
                                       uint8_t* Els, float* crow,
                                       int w, int lane) {
    // lw/lb loads issued FIRST so they're in flight during the whole sort.
    const float4* lw4 = reinterpret_cast<const float4*>(lw + lane * 8);
    const float4* lb4 = reinterpret_cast<const float4*>(lb + lane * 8);
    float4 wa = lw4[0], wb = lw4[1], ba = lb4[0], bbv = lb4[1];

    float h[8], v[8];
    {
        const float* hp = hbuf + w * 512 + lane * 8;
        float4 a = *reinterpret_cast<const float4*>(hp);
        float4 b = *reinterpret_cast<const float4*>(hp + 4);
        h[0] = a.x; h[1] = a.y; h[2] = a.z; h[3] = a.w;
        h[4] = b.x; h[5] = b.y; h[6] = b.z; h[7] = b.w;
#pragma unroll
        for (int j = 0; j < 8; ++j) v[j] = h[j];
    }
    // Bitonic sort of 512 values, element e = lane*8 + j, ascending.
    // Runtime k/jj loops; all v[] indices remain compile-time constants.
#pragma clang loop unroll(disable)
    for (int k = 2; k <= 512; k <<= 1) {
#pragma clang loop unroll(disable)
        for (int jj = (k >> 1); jj > 0; jj >>= 1) {
            if (jj >= 8) {
                int lm = jj >> 3;
                bool low = ((lane & lm) == 0);
#pragma unroll
                for (int j = 0; j < 8; ++j) {
                    float pv = __shfl_xor(v[j], lm);
                    bool up = ((((lane << 3) | j) & k) == 0);
                    v[j] = (up == low) ? fminf(v[j], pv) : fmaxf(v[j], pv);
                }
            } else if (jj == 4) {
#pragma unroll
                for (int j = 0; j < 4; ++j) {
                    bool up = ((((lane << 3) | j) & k) == 0);
                    float a = v[j], c = v[j + 4];
                    float lo = fminf(a, c), hi = fmaxf(a, c);
                    v[j] = up ? lo : hi;
                    v[j + 4] = up ? hi : lo;
                }
            } else if (jj == 2) {
#pragma unroll
                for (int jb = 0; jb < 8; jb += 4)
#pragma unroll
                    for (int j0 = 0; j0 < 2; ++j0) {
                        int j = jb + j0;
                        bool up = ((((lane << 3) | j) & k) == 0);
                        float a = v[j], c = v[j + 2];
                        float lo = fminf(a, c), hi = fmaxf(a, c);
                        v[j] = up ? lo : hi;
                        v[j + 2] = up ? hi : lo;
                    }
            } else {  // jj == 1
#pragma unroll
                for (int j = 0; j < 8; j += 2) {
                    bool up = ((((lane << 3) | j) & k) == 0);
                    float a = v[j], c = v[j + 1];
                    float lo = fminf(a, c), hi = fmaxf(a, c);
                    v[j] = up ? lo : hi;
                    v[j + 1] = up ? hi : lo;
                }
            }
        }
    }
    float s127 = __shfl(v[7], 15);
    float s128 = __shfl(v[0], 16);
    float med  = __shfl(v[7], 31);
    float s383 = __shfl(v[7], 47);
    float s384 = __shfl(v[0], 48);
    float q25 = s127 + 0.75f * (s128 - s127);
    float q75 = s383 + 0.25f * (s384 - s383);
    float inv = 1.0f / fmaxf(q75 - q25, 1e-6f);

    float y[8], cm = 0.0f;                      // y >= 0 after relu
    {
        float lwv[8] = {wa.x, wa.y, wa.z, wa.w, wb.x, wb.y, wb.z, wb.w};
        float lbv[8] = {ba.x, ba.y, ba.z, ba.w, bbv.x, bbv.y, bbv.z, bbv.w};
#pragma unroll
        for (int j = 0; j < 8; ++j) {
            y[j] = fmaxf((h[j] - med) * inv * lwv[j] + lbv[j], 0.0f);
            cm = fmaxf(cm, y[j]);
        }
    }
#pragma unroll
    for (int s = 32; s > 0; s >>= 1) cm = fmaxf(cm, __shfl_xor(cm, s));
    {
        float e[8];
#pragma unroll
        for (int j = 0; j < 8; ++j) e[j] = 64.0f * __expf(y[j] - cm);
        int2 o;
        o.x = pk4_fp8(e[0], e[1], e[2], e[3]);
        o.y = pk4_fp8(e[4], e[5], e[6], e[7]);
        *reinterpret_cast<int2*>(&Els[w * ELS_B + lane * 8]) = o;
    }
    if (lane == 0) crow[w] = cm;
}

__global__ __launch_bounds__(512, 4) void fused_rows(
    const float* __restrict__ x,
    const float* __restrict__ b1,
    const float* __restrict__ ln1w, const float* __restrict__ ln1b,
    const float* __restrict__ b2,
    const float* __restrict__ ln2w, const float* __restrict__ ln2b,
    const float* __restrict__ b3,
    const uint8_t* __restrict__ Ew,
    float* __restrict__ out)
{
    __shared__ uint8_t Els[2 * ELS_B];         // fp8 activations (2 rows)
    __shared__ float hbuf[2 * 512];            // pre-LN layer output
    __shared__ float crow[2];                  // per-row shift (last LN)

    const int tid = threadIdx.x;
    const int lane = tid & 63;
    const int w = tid >> 6;                    // wave id 0..7
    const int r = lane & 15, q = lane >> 4;
    const int blk = blockIdx.x;                // rows 2*blk .. 2*blk+1

    const uint8_t* bp1 = Ew + lane * 8;
    const uint8_t* bp2 = bp1 + 262144;
    const uint8_t* bp3 = bp1 + 524288;

    long bb[8][4];
    long areg[16];
    v4f acc[4];

    // ---- layer-1 B prefetch in flight during the exp(x) prologue ----
    prefetchB<4>(bp1, w * 4, bb);

    // ---- phase 0: A1 = fp8(4*exp(x)) for this block's 2 rows ----
    // (+ln4 shift cancels in LN1's median subtraction; keeps fp8 normal-range)
    if (tid < 256) {
        int row = tid >> 7, col = (tid & 127) * 4;
        float4 a = *reinterpret_cast<const float4*>(x + blk * 1024 + row * 512 + col);
        *reinterpret_cast<int*>(&Els[row * ELS_B + col]) =
            pk4_fp8(4.0f * __expf(a.x), 4.0f * __expf(a.y),
                    4.0f * __expf(a.z), 4.0f * __expf(a.w));
    }
    __syncthreads();

    // ===== layer 1: wave w covers cols w*64..w*64+64 (tiles w*4..w*4+4) =====
    load_areg(Els, lane, areg);
    gemm_body<4>(bp1, w * 4, areg, bb, acc);
    if (q == 0) {
#pragma unroll
        for (int s = 0; s < 4; ++s) {
            int col = (w * 4 + s) * 16 + r;
            float bbv = b1[col];
#pragma unroll
            for (int t = 0; t < 2; ++t)        // C rows 0,1 = data rows 0,1
                hbuf[t * 512 + col] = __logf(acc[s][t]) + bbv;
        }
    }
    prefetchB<4>(bp2, w * 4, bb);              // layer-2 B rides over LN1
    __syncthreads();
    if (w < 2) ln_row(hbuf, ln1w, ln1b, Els, crow, w, lane);
    __syncthreads();

    // ===== layer 2 (uniform ln64 - cm1 shift absorbed by LN2's median) =====
    load_areg(Els, lane, areg);
    gemm_body<4>(bp2, w * 4, areg, bb, acc);
    if (q == 0) {
#pragma unroll
        for (int s = 0; s < 4; ++s) {
            int col = (w * 4 + s) * 16 + r;
            float bbv = b2[col];
#pragma unroll
            for (int t = 0; t < 2; ++t)
                hbuf[t * 512 + col] = __logf(acc[s][t]) + bbv;
        }
    }
    prefetchB<2>(bp3, w * 2, bb);              // layer-3 B rides over LN2
    __syncthreads();
    if (w < 2) ln_row(hbuf, ln2w, ln2b, Els, crow, w, lane);
    __syncthreads();

    // ===== layer 3 (N=256, tiles w*2..w*2+2): out = log(acc)+cm2-ln64+b3 =====
    load_areg(Els, lane, areg);
    gemm_body<2>(bp3, w * 2, areg, bb, acc);
    if (q == 0) {
#pragma unroll
        for (int s = 0; s < 2; ++s) {
            int col = (w * 2 + s) * 16 + r;
            float bbv = b3[col] - LN64f;
#pragma unroll
            for (int t = 0; t < 2; ++t)
                out[(blk * 2 + t) * 256 + col] = __logf(acc[s][t]) + crow[t] + bbv;
        }
    }
}

extern "C" void kernel_launch(void* const* d_in, const int* in_sizes, int n_in,
                              void* d_out, int out_size, void* d_ws, size_t ws_size,
                              hipStream_t stream) {
    const float* x    = (const float*)d_in[0];
    const float* w1   = (const float*)d_in[1];
    const float* b1   = (const float*)d_in[2];
    const float* ln1w = (const float*)d_in[3];
    const float* ln1b = (const float*)d_in[4];
    const float* w2   = (const float*)d_in[5];
    const float* b2   = (const float*)d_in[6];
    const float* ln2w = (const float*)d_in[7];
    const float* ln2b = (const float*)d_in[8];
    const float* w3   = (const float*)d_in[9];
    const float* b3   = (const float*)d_in[10];
    float* out = (float*)d_out;

    uint8_t* Ew = (uint8_t*)d_ws;              // 655360 B fp8 = 640 KB

    expW_frag<<<320, 256, 0, stream>>>(w1, w2, w3, Ew);
    fused_rows<<<512, 512, 0, stream>>>(x, b1, ln1w, ln1b, b2, ln2w, ln2b,
                                        b3, Ew, out);
}

// Round 3
// 105.104 us; speedup vs baseline: 1.0640x; 1.0640x over previous
//
#include <hip/hip_runtime.h>
#include <math.h>

// ---------------------------------------------------------------------------
// TropicalMLP: h_i = logsumexp_j(x_j + w_ij) + b_i = log(sum_j e^x_j e^w_ij)+b_i
// Row-independent network: one block owns 2 batch rows, runs all 3 layers +
// 2 tropical-LNs with only __syncthreads(). Two dispatches.
// fp8 e4m3 operands via mfma_f32_16x16x32_fp8_fp8.
// Scaling keeps fp8 normal-range: layer1 A = 4*exp(x) (+ln4 cancels in LN1
// median); layers2/3 A = 64*exp(y-cm) (+ln64 cancels in LN2; subtracted in
// final epilogue). B = exp(w) in [0.6,1.6] needs no scale.
// Weights pre-exp'd + permuted to MFMA-fragment order (512B-coalesced loads).
// R8: B-prefetch for each layer hoisted ABOVE the preceding barrier.
// R9: bitonic sort as compact runtime loops (I-footprint fix; -10%).
// R10: 2 rows/block x 512 blocks = 2 blocks/CU (TLP; -11%).
// R11: LN WAVE-PARALLELIZATION. Counters still latency-bound (MfmaUtil 9%,
// VALU 22%, HBM 1.5%): the sort ran on 2/8 waves, 8 elem/lane (8 dependent
// bpermutes/round x 21 rounds). Now 4 waves/row, 2 elem/lane: 42/45 rounds
// are 2-shuffle or in-lane; the 3 jj>=128 rounds are LDS exchanges through
// hbuf (h kept in regs). All 8 waves busy; order stats via LDS broadcast.
// GEMM epilogue also spread across q-groups (subtile s=q, ternary select --
// no runtime reg indexing).
// ---------------------------------------------------------------------------

typedef float v4f __attribute__((ext_vector_type(4)));

#define ELS_B 528                  // bytes per LDS A-row (16B pad: 2-way banks = free)
#define LN64f 4.1588830833596715f  // ln(64)

__device__ __forceinline__ int pk4_fp8(float a, float b, float c, float d) {
    int p = __builtin_amdgcn_cvt_pk_fp8_f32(a, b, 0, 0);      // bytes 0,1
    p = __builtin_amdgcn_cvt_pk_fp8_f32(c, d, p, 1);          // bytes 2,3
    return p;
}

// D1: exp + fp8 + fragment reorder. Global 16-col tile S, k-step t (32 k),
// lane l = q*16+r:  Ef[(S*16+t)*512 + l*8 + j] = fp8(exp(W[S*16+r][t*32+q*8+j]))
// S: 0..31 -> w1, 32..63 -> w2, 64..79 -> w3 (contiguous per layer, in bytes).
__global__ __launch_bounds__(256) void expW_frag(const float* __restrict__ w1,
                                                 const float* __restrict__ w2,
                                                 const float* __restrict__ w3,
                                                 uint8_t* __restrict__ Ef) {
    int u = blockIdx.x * 256 + threadIdx.x;          // 0..81919 (320 blocks)
    int lane = u & 63, t = (u >> 6) & 15, S = u >> 10;
    int r = lane & 15, q = lane >> 4;
    const float* w; int tile;
    if (S < 32)      { w = w1; tile = S; }
    else if (S < 64) { w = w2; tile = S - 32; }
    else             { w = w3; tile = S - 64; }
    const float* src = w + (tile * 16 + r) * 512 + t * 32 + q * 8;
    float4 a = *reinterpret_cast<const float4*>(src);
    float4 b = *reinterpret_cast<const float4*>(src + 4);
    int2 o;
    o.x = pk4_fp8(__expf(a.x), __expf(a.y), __expf(a.z), __expf(a.w));
    o.y = pk4_fp8(__expf(b.x), __expf(b.y), __expf(b.z), __expf(b.w));
    *reinterpret_cast<int2*>(Ef + u * 8) = o;
}

// Preload whole A operand (2 rows dup'd 8x in the 16-row slot) for all 16
// k-steps: 16 x ds_read_b64.
__device__ __forceinline__ void load_areg(const uint8_t* Els, int lane, long* areg) {
    const uint8_t* ap = Els + (lane & 1) * ELS_B + ((lane >> 4) & 3) * 8;
#pragma unroll
    for (int t = 0; t < 16; ++t)
        areg[t] = *reinterpret_cast<const long*>(ap + t * 32);
}

// Issue the first 8 k-steps of a layer's B stream (kept in flight across the
// following barrier / LN — this is the latency-hiding hoist).
template <int NSUB>
__device__ __forceinline__ void prefetchB(const uint8_t* __restrict__ bp,
                                          int s0, long bb[8][4]) {
#pragma unroll
    for (int p = 0; p < 8; ++p)
#pragma unroll
        for (int s = 0; s < NSUB; ++s)
            bb[p][s] = *reinterpret_cast<const long*>(bp + ((s0 + s) * 16 + p) * 512);
}

// C[16(dup rows) x NSUB*16 cols] over K=512, fp8 MFMA, consuming the
// prefetched pipe and rolling it forward (depth 8).
template <int NSUB>
__device__ __forceinline__ void gemm_body(const uint8_t* __restrict__ bp,
                                          int s0, const long* areg,
                                          long bb[8][4], v4f* acc) {
#pragma unroll
    for (int s = 0; s < NSUB; ++s) acc[s] = (v4f){0.f, 0.f, 0.f, 0.f};
#pragma unroll
    for (int t = 0; t < 16; ++t) {
        long a = areg[t];
        long bcur[NSUB];
#pragma unroll
        for (int s = 0; s < NSUB; ++s) bcur[s] = bb[t & 7][s];
        if (t < 8) {
#pragma unroll
            for (int s = 0; s < NSUB; ++s)
                bb[t & 7][s] =
                    *reinterpret_cast<const long*>(bp + ((s0 + s) * 16 + t + 8) * 512);
        }
#pragma unroll
        for (int s = 0; s < NSUB; ++s)
            acc[s] = __builtin_amdgcn_mfma_f32_16x16x32_fp8_fp8(a, bcur[s],
                                                                acc[s], 0, 0, 0);
    }
}

// In-wave bitonic rounds for stage k: jj = jjhi..2 via shfl (lm = jj/2 lane
// mask), then jj=1 in-lane. 2 elements/lane, e = ebase + {0,1}.
__device__ __forceinline__ void sort_shuf(float& v0, float& v1, int lane,
                                          int ebase, int k, int jjhi) {
#pragma clang loop unroll(disable)
    for (int jj = jjhi; jj >= 2; jj >>= 1) {
        int lm = jj >> 1;
        bool keepmin = (((ebase & k) == 0) == ((lane & lm) == 0));
        float p0 = __shfl_xor(v0, lm);
        float p1 = __shfl_xor(v1, lm);
        v0 = keepmin ? fminf(v0, p0) : fmaxf(v0, p0);
        v1 = keepmin ? fminf(v1, p1) : fmaxf(v1, p1);
    }
    bool up = ((ebase & k) == 0);
    float lo = fminf(v0, v1), hi = fmaxf(v0, v1);
    v0 = up ? lo : hi;
    v1 = up ? hi : lo;
}

// Tropical-LN on one row, 4 waves cooperating (W = wave-in-row 0..3), 2
// elements/lane: exact order stats via bitonic sort; jj>=128 rounds exchange
// through hb (LDS); relu; subtract rowmax; 64*exp -> fp8 into Els.
// MUST be called by all 8 waves (internal __syncthreads).
__device__ __forceinline__ void ln_row4(float* hb,   // hbuf + row*512
                                        const float* __restrict__ lw,
                                        const float* __restrict__ lb,
                                        uint8_t* Els_row, float* crow_row,
                                        float* cmx_row,           // [4]
                                        int W, int lane) {
    const int e0 = W * 128 + lane * 2;
    float2 lwv = *reinterpret_cast<const float2*>(lw + e0);
    float2 lbv = *reinterpret_cast<const float2*>(lb + e0);
    float2 hv = *reinterpret_cast<const float2*>(hb + e0);
    float h0 = hv.x, h1 = hv.y, v0 = h0, v1 = h1;

    // Phase A: k = 2..128 (all rounds within a wave).
#pragma clang loop unroll(disable)
    for (int k = 2; k <= 128; k <<= 1)
        sort_shuf(v0, v1, lane, e0, k, (k >> 1) > 64 ? 64 : (k >> 1));

    // Phase B: k = 256. jj=128 exchange via LDS, then in-wave.
    __syncthreads();                           // everyone's initial hb reads done
    *reinterpret_cast<float2*>(hb + e0) = make_float2(v0, v1);
    __syncthreads();
    {
        bool keepmin = (((e0 & 256) == 0) == ((e0 & 128) == 0));
        float2 p = *reinterpret_cast<const float2*>(hb + (e0 ^ 128));
        v0 = keepmin ? fminf(v0, p.x) : fmaxf(v0, p.x);
        v1 = keepmin ? fminf(v1, p.y) : fmaxf(v1, p.y);
    }
    sort_shuf(v0, v1, lane, e0, 256, 64);

    // Phase C: k = 512. jj=256 and jj=128 exchanges, then in-wave.
    __syncthreads();
    *reinterpret_cast<float2*>(hb + e0) = make_float2(v0, v1);
    __syncthreads();
    {
        bool keepmin = ((e0 & 256) == 0);      // ascending final stage
        float2 p = *reinterpret_cast<const float2*>(hb + (e0 ^ 256));
        v0 = keepmin ? fminf(v0, p.x) : fmaxf(v0, p.x);
        v1 = keepmin ? fminf(v1, p.y) : fmaxf(v1, p.y);
    }
    __syncthreads();
    *reinterpret_cast<float2*>(hb + e0) = make_float2(v0, v1);
    __syncthreads();
    {
        bool keepmin = ((e0 & 128) == 0);
        float2 p = *reinterpret_cast<const float2*>(hb + (e0 ^ 128));
        v0 = keepmin ? fminf(v0, p.x) : fmaxf(v0, p.x);
        v1 = keepmin ? fminf(v1, p.y) : fmaxf(v1, p.y);
    }
    sort_shuf(v0, v1, lane, e0, 512, 64);

    // Write-back + order-stat broadcast reads.
    __syncthreads();
    *reinterpret_cast<float2*>(hb + e0) = make_float2(v0, v1);
    __syncthreads();
    float s127 = hb[127], s128 = hb[128], med = hb[255];
    float s383 = hb[383], s384 = hb[384];
    float q25 = s127 + 0.75f * (s128 - s127);
    float q75 = s383 + 0.25f * (s384 - s383);
    float inv = 1.0f / fmaxf(q75 - q25, 1e-6f);

    float y0 = fmaxf((h0 - med) * inv * lwv.x + lbv.x, 0.0f);
    float y1 = fmaxf((h1 - med) * inv * lwv.y + lbv.y, 0.0f);
    float cm = fmaxf(y0, y1);
#pragma unroll
    for (int s = 32; s > 0; s >>= 1) cm = fmaxf(cm, __shfl_xor(cm, s));
    if (lane == 0) cmx_row[W] = cm;
    __syncthreads();
    cm = fmaxf(fmaxf(cmx_row[0], cmx_row[1]), fmaxf(cmx_row[2], cmx_row[3]));

    int p = __builtin_amdgcn_cvt_pk_fp8_f32(64.0f * __expf(y0 - cm),
                                            64.0f * __expf(y1 - cm), 0, 0);
    *reinterpret_cast<ushort*>(Els_row + e0) = (ushort)p;
    if (lane == 0 && W == 0) crow_row[0] = cm;
}

__global__ __launch_bounds__(512, 4) void fused_rows(
    const float* __restrict__ x,
    const float* __restrict__ b1,
    const float* __restrict__ ln1w, const float* __restrict__ ln1b,
    const float* __restrict__ b2,
    const float* __restrict__ ln2w, const float* __restrict__ ln2b,
    const float* __restrict__ b3,
    const uint8_t* __restrict__ Ew,
    float* __restrict__ out)
{
    __shared__ uint8_t Els[2 * ELS_B];         // fp8 activations (2 rows)
    __shared__ float hbuf[2 * 512];            // pre-LN layer output / sort scratch
    __shared__ float crow[2];                  // per-row shift (last LN)
    __shared__ float cmx[2][4];                // per-row per-wave max partials

    const int tid = threadIdx.x;
    const int lane = tid & 63;
    const int w = tid >> 6;                    // wave id 0..7
    const int r = lane & 15, q = lane >> 4;
    const int row = w >> 2, W = w & 3;         // LN decomposition
    const int blk = blockIdx.x;                // rows 2*blk .. 2*blk+1

    const uint8_t* bp1 = Ew + lane * 8;
    const uint8_t* bp2 = bp1 + 262144;
    const uint8_t* bp3 = bp1 + 524288;

    long bb[8][4];
    long areg[16];
    v4f acc[4];

    // ---- layer-1 B prefetch in flight during the exp(x) prologue ----
    prefetchB<4>(bp1, w * 4, bb);

    // ---- phase 0: A1 = fp8(4*exp(x)) for this block's 2 rows ----
    // (+ln4 shift cancels in LN1's median subtraction; keeps fp8 normal-range)
    if (tid < 256) {
        int rr = tid >> 7, col = (tid & 127) * 4;
        float4 a = *reinterpret_cast<const float4*>(x + blk * 1024 + rr * 512 + col);
        *reinterpret_cast<int*>(&Els[rr * ELS_B + col]) =
            pk4_fp8(4.0f * __expf(a.x), 4.0f * __expf(a.y),
                    4.0f * __expf(a.z), 4.0f * __expf(a.w));
    }
    __syncthreads();

    // ===== layer 1: wave w covers cols w*64..w*64+64 (tiles w*4..w*4+4) =====
    load_areg(Els, lane, areg);
    gemm_body<4>(bp1, w * 4, areg, bb, acc);
    {   // epilogue spread over q-groups: lane group q owns subtile s=q.
        // C row q*4+t = data row t&1 (A rows alternate row0,row1).
        v4f av = (q == 0) ? acc[0] : (q == 1) ? acc[1] : (q == 2) ? acc[2] : acc[3];
        int col = (w * 4 + q) * 16 + r;
        float bbv = b1[col];
        hbuf[col]       = __logf(av[0]) + bbv;
        hbuf[512 + col] = __logf(av[1]) + bbv;
    }
    prefetchB<4>(bp2, w * 4, bb);              // layer-2 B rides over LN1
    __syncthreads();
    ln_row4(hbuf + row * 512, ln1w, ln1b, Els + row * ELS_B,
            crow + row, cmx[row], W, lane);
    __syncthreads();

    // ===== layer 2 (uniform ln64 - cm1 shift absorbed by LN2's median) =====
    load_areg(Els, lane, areg);
    gemm_body<4>(bp2, w * 4, areg, bb, acc);
    {
        v4f av = (q == 0) ? acc[0] : (q == 1) ? acc[1] : (q == 2) ? acc[2] : acc[3];
        int col = (w * 4 + q) * 16 + r;
        float bbv = b2[col];
        hbuf[col]       = __logf(av[0]) + bbv;
        hbuf[512 + col] = __logf(av[1]) + bbv;
    }
    prefetchB<2>(bp3, w * 2, bb);              // layer-3 B rides over LN2
    __syncthreads();
    ln_row4(hbuf + row * 512, ln2w, ln2b, Els + row * ELS_B,
            crow + row, cmx[row], W, lane);
    __syncthreads();

    // ===== layer 3 (N=256, tiles w*2..w*2+2): out = log(acc)+cm2-ln64+b3 =====
    load_areg(Els, lane, areg);
    gemm_body<2>(bp3, w * 2, areg, bb, acc);
    if (q < 2) {
        v4f av = (q == 0) ? acc[0] : acc[1];
        int col = (w * 2 + q) * 16 + r;
        float bbv = b3[col] - LN64f;
        out[(blk * 2 + 0) * 256 + col] = __logf(av[0]) + crow[0] + bbv;
        out[(blk * 2 + 1) * 256 + col] = __logf(av[1]) + crow[1] + bbv;
    }
}

extern "C" void kernel_launch(void* const* d_in, const int* in_sizes, int n_in,
                              void* d_out, int out_size, void* d_ws, size_t ws_size,
                              hipStream_t stream) {
    const float* x    = (const float*)d_in[0];
    const float* w1   = (const float*)d_in[1];
    const float* b1   = (const float*)d_in[2];
    const float* ln1w = (const float*)d_in[3];
    const float* ln1b = (const float*)d_in[4];
    const float* w2   = (const float*)d_in[5];
    const float* b2   = (const float*)d_in[6];
    const float* ln2w = (const float*)d_in[7];
    const float* ln2b = (const float*)d_in[8];
    const float* w3   = (const float*)d_in[9];
    const float* b3   = (const float*)d_in[10];
    float* out = (float*)d_out;

    uint8_t* Ew = (uint8_t*)d_ws;              // 655360 B fp8 = 640 KB

    expW_frag<<<320, 256, 0, stream>>>(w1, w2, w3, Ew);
    fused_rows<<<512, 512, 0, stream>>>(x, b1, ln1w, ln1b, b2, ln2w, ln2b,
                                        b3, Ew, out);
}